// Round 1
// baseline (301.367 us; speedup 1.0000x reference)
//
#include <hip/hip_runtime.h>

#define N_DIM 8192   // rows of features / columns of w / output length
#define K_DIM 512    // inner dim of features @ E
#define D_DIM 4096   // columns of E / rows of w

typedef __bf16 bf16x8 __attribute__((ext_vector_type(8)));
typedef float  f32x4  __attribute__((ext_vector_type(4)));

__device__ __forceinline__ unsigned short f2bf(float f) {
    union { float f; unsigned int u; } v; v.f = f;
    unsigned int r = v.u + 0x7FFF + ((v.u >> 16) & 1);   // RNE
    return (unsigned short)(r >> 16);
}

// ---------------------------------------------------------------------------
// Kernel 1: E [512][4096] f32  ->  ET [4096][512] bf16 (k-contiguous rows)
// ---------------------------------------------------------------------------
__global__ __launch_bounds__(256) void transpose_E(const float* __restrict__ E,
                                                   unsigned short* __restrict__ ET) {
    __shared__ float tile[64][65];
    const int d0 = blockIdx.x * 64;
    const int k0 = blockIdx.y * 64;
    const int tid = threadIdx.x;
    const int r  = tid / 16;          // 0..15
    const int c4 = (tid % 16) * 4;    // 0..60
#pragma unroll
    for (int p = 0; p < 4; ++p) {
        int k = p * 16 + r;
        float4 v = *reinterpret_cast<const float4*>(E + (size_t)(k0 + k) * D_DIM + d0 + c4);
        tile[k][c4 + 0] = v.x; tile[k][c4 + 1] = v.y;
        tile[k][c4 + 2] = v.z; tile[k][c4 + 3] = v.w;
    }
    __syncthreads();
#pragma unroll
    for (int p = 0; p < 4; ++p) {
        int d = p * 16 + r;
        ushort4 o;
        o.x = f2bf(tile[c4 + 0][d]);
        o.y = f2bf(tile[c4 + 1][d]);
        o.z = f2bf(tile[c4 + 2][d]);
        o.w = f2bf(tile[c4 + 3][d]);
        *reinterpret_cast<ushort4*>(ET + (size_t)(d0 + d) * K_DIM + k0 + c4) = o;
    }
}

// ---------------------------------------------------------------------------
// Kernel 2: fused  out[n] = sum_d (F@E + b)[n,d] * w[d,n]
// C-tile 128(n-rows) x 128(d-cols), BK=32, 4 waves (2x2), 16x16x32 bf16 MFMA.
// Epilogue multiplies by f32 w-tile + b and atomically reduces into out.
// ---------------------------------------------------------------------------
__global__ __launch_bounds__(256) void gemm_fused(const float* __restrict__ F,
                                                  const float* __restrict__ W,
                                                  const unsigned short* __restrict__ ET,
                                                  const float* __restrict__ B,
                                                  float* __restrict__ out) {
    __shared__ unsigned short Ash[128 * 32];  // [n-row][k] k-contiguous, 64B rows
    __shared__ unsigned short Bsh[128 * 32];  // [d-row][k] k-contiguous, 64B rows

    const int tid  = threadIdx.x;
    const int wave = tid >> 6;
    const int lane = tid & 63;
    const int wy   = wave >> 1;     // n-direction wave coord (0..1)
    const int wx   = wave & 1;      // d-direction wave coord (0..1)
    const int l15  = lane & 15;
    const int quad = lane >> 4;

    const int d0 = blockIdx.x * 128;   // d tile base
    const int n0 = blockIdx.y * 128;   // n tile base

    f32x4 acc[4][4] = {};

    const int arow = tid >> 3;          // 0..31
    const int ak4  = (tid & 7) * 4;     // 0..28

    for (int kt = 0; kt < K_DIM / 32; ++kt) {
        const int kbase = kt * 32;

        // --- B-tile: async global->LDS, bf16 already transposed (ET) ---
#pragma unroll
        for (int jj = 0; jj < 2; ++jj) {
            int j = wave * 2 + jj;      // 0..7, each inst fills 16 rows x 64B
            const unsigned short* gp =
                ET + (size_t)(d0 + j * 16 + (lane >> 2)) * K_DIM + kbase + (lane & 3) * 8;
            __builtin_amdgcn_global_load_lds(
                (const __attribute__((address_space(1))) void*)gp,
                (__attribute__((address_space(3))) void*)(Bsh + j * 512),
                16, 0, 0);
        }

        // --- A-tile: f32 F -> bf16 -> LDS (VGPR round-trip for convert) ---
        float4 av[4];
#pragma unroll
        for (int p = 0; p < 4; ++p) {
            int row = arow + 32 * p;
            av[p] = *reinterpret_cast<const float4*>(
                F + (size_t)(n0 + row) * K_DIM + kbase + ak4);
        }
#pragma unroll
        for (int p = 0; p < 4; ++p) {
            int row = arow + 32 * p;
            ushort4 o;
            o.x = f2bf(av[p].x); o.y = f2bf(av[p].y);
            o.z = f2bf(av[p].z); o.w = f2bf(av[p].w);
            *reinterpret_cast<ushort4*>(Ash + row * 32 + ak4) = o;
        }
        __syncthreads();

        // --- fragments + MFMA ---
        bf16x8 af[4], bf[4];
#pragma unroll
        for (int mi = 0; mi < 4; ++mi)
            af[mi] = *reinterpret_cast<const bf16x8*>(
                Ash + (wy * 64 + mi * 16 + l15) * 32 + quad * 8);
#pragma unroll
        for (int ni = 0; ni < 4; ++ni)
            bf[ni] = *reinterpret_cast<const bf16x8*>(
                Bsh + (wx * 64 + ni * 16 + l15) * 32 + quad * 8);
#pragma unroll
        for (int mi = 0; mi < 4; ++mi)
#pragma unroll
            for (int ni = 0; ni < 4; ++ni)
                acc[mi][ni] = __builtin_amdgcn_mfma_f32_16x16x32_bf16(
                    af[mi], bf[ni], acc[mi][ni], 0, 0, 0);
        __syncthreads();
    }

    // --- fused epilogue: out[n] += sum_d (y[n,d] + b[d]) * w[d,n] ---
    // C layout (16x16x32): col(d) = lane&15, row(n) = quad*4 + reg
    float part[4][4] = {};   // [mi][r]
#pragma unroll
    for (int ni = 0; ni < 4; ++ni) {
        const int d = d0 + wx * 64 + ni * 16 + l15;
        const float bd = B[d];
        const float* wrow = W + (size_t)d * N_DIM;
#pragma unroll
        for (int mi = 0; mi < 4; ++mi) {
            const int nb = n0 + wy * 64 + mi * 16 + quad * 4;
            float4 w4 = *reinterpret_cast<const float4*>(wrow + nb);
            part[mi][0] += (acc[mi][ni][0] + bd) * w4.x;
            part[mi][1] += (acc[mi][ni][1] + bd) * w4.y;
            part[mi][2] += (acc[mi][ni][2] + bd) * w4.z;
            part[mi][3] += (acc[mi][ni][3] + bd) * w4.w;
        }
    }
    // reduce across the 16 lanes (d-direction) sharing each n, then one atomic
#pragma unroll
    for (int mi = 0; mi < 4; ++mi) {
#pragma unroll
        for (int r = 0; r < 4; ++r) {
            float v = part[mi][r];
            v += __shfl_xor(v, 1);
            v += __shfl_xor(v, 2);
            v += __shfl_xor(v, 4);
            v += __shfl_xor(v, 8);
            if (l15 == 0)
                atomicAdd(out + n0 + wy * 64 + mi * 16 + quad * 4 + r, v);
        }
    }
}

extern "C" void kernel_launch(void* const* d_in, const int* in_sizes, int n_in,
                              void* d_out, int out_size, void* d_ws, size_t ws_size,
                              hipStream_t stream) {
    const float* F = (const float*)d_in[0];   // features (N, K)
    const float* W = (const float*)d_in[1];   // w        (D, N)
    const float* E = (const float*)d_in[2];   // E        (K, D)
    const float* B = (const float*)d_in[3];   // b        (D,)
    float* out = (float*)d_out;               // (N,) f32

    unsigned short* ET = (unsigned short*)d_ws;   // bf16 (D, K) = 4 MB

    // out is re-poisoned to 0xAA before every launch -> zero it (atomic target)
    hipMemsetAsync(d_out, 0, (size_t)out_size * sizeof(float), stream);

    transpose_E<<<dim3(D_DIM / 64, K_DIM / 64), 256, 0, stream>>>(E, ET);
    gemm_fused<<<dim3(D_DIM / 128, N_DIM / 128), 256, 0, stream>>>(F, W, ET, B, out);
}

// Round 2
// 248.210 us; speedup vs baseline: 1.2142x; 1.2142x over previous
//
#include <hip/hip_runtime.h>

#define N_DIM 8192   // rows of features / columns of w / output length
#define K_DIM 512    // inner dim of features @ E
#define D_DIM 4096   // columns of E / rows of w

typedef __bf16 bf16x8 __attribute__((ext_vector_type(8)));
typedef float  f32x16 __attribute__((ext_vector_type(16)));
typedef unsigned short u16x8 __attribute__((ext_vector_type(8)));

__device__ __forceinline__ unsigned short f2bf(float f) {
    union { float f; unsigned int u; } v; v.f = f;
    unsigned int r = v.u + 0x7FFF + ((v.u >> 16) & 1);   // RNE
    return (unsigned short)(r >> 16);
}

// ---------------------------------------------------------------------------
// Kernel 1: E [512][4096] f32  ->  ET [4096][512] bf16 (k-contiguous rows)
// ---------------------------------------------------------------------------
__global__ __launch_bounds__(256) void transpose_E(const float* __restrict__ E,
                                                   unsigned short* __restrict__ ET) {
    __shared__ float tile[64][65];
    const int d0 = blockIdx.x * 64;
    const int k0 = blockIdx.y * 64;
    const int tid = threadIdx.x;
    const int r  = tid / 16;          // 0..15
    const int c4 = (tid % 16) * 4;    // 0..60
#pragma unroll
    for (int p = 0; p < 4; ++p) {
        int k = p * 16 + r;
        float4 v = *reinterpret_cast<const float4*>(E + (size_t)(k0 + k) * D_DIM + d0 + c4);
        tile[k][c4 + 0] = v.x; tile[k][c4 + 1] = v.y;
        tile[k][c4 + 2] = v.z; tile[k][c4 + 3] = v.w;
    }
    __syncthreads();
#pragma unroll
    for (int p = 0; p < 4; ++p) {
        int d = p * 16 + r;
        ushort4 o;
        o.x = f2bf(tile[c4 + 0][d]);
        o.y = f2bf(tile[c4 + 1][d]);
        o.z = f2bf(tile[c4 + 2][d]);
        o.w = f2bf(tile[c4 + 3][d]);
        *reinterpret_cast<ushort4*>(ET + (size_t)(d0 + d) * K_DIM + k0 + c4) = o;
    }
}

// ---------------------------------------------------------------------------
// Kernel 2: F [8192][512] f32 -> FB bf16, same layout (k-contiguous rows)
// ---------------------------------------------------------------------------
__global__ __launch_bounds__(256) void convert_F(const float* __restrict__ F,
                                                 unsigned short* __restrict__ FB) {
    const int idx8 = (blockIdx.x * 256 + threadIdx.x) * 8;
    float4 a = *reinterpret_cast<const float4*>(F + idx8);
    float4 b = *reinterpret_cast<const float4*>(F + idx8 + 4);
    u16x8 o;
    o[0] = f2bf(a.x); o[1] = f2bf(a.y); o[2] = f2bf(a.z); o[3] = f2bf(a.w);
    o[4] = f2bf(b.x); o[5] = f2bf(b.y); o[6] = f2bf(b.z); o[7] = f2bf(b.w);
    *reinterpret_cast<u16x8*>(FB + idx8) = o;
}

// ---------------------------------------------------------------------------
// Kernel 3: fused  out[n] = sum_d (F@E + b)[n,d] * w[d,n], computed as y^T:
// C-tile 128(d-rows) x 128(n-cols), BK=64 (two 32-k panels of 64B rows),
// 4 waves (2x2), 32x32x16 bf16 MFMA. C cols = n -> coalesced W epilogue.
// ---------------------------------------------------------------------------
__global__ __launch_bounds__(256) void gemm_fused(const unsigned short* __restrict__ FB,
                                                  const float* __restrict__ W,
                                                  const unsigned short* __restrict__ ET,
                                                  const float* __restrict__ B,
                                                  float* __restrict__ out) {
    // panel p (k 32p..32p+31): [128 rows][32 shorts] = 8 KB; two panels each for A,B
    __shared__ unsigned short Ash[2 * 128 * 32];  // ET tile: rows = d
    __shared__ unsigned short Bsh[2 * 128 * 32];  // FB tile: rows = n

    const int tid  = threadIdx.x;
    const int wave = tid >> 6;
    const int lane = tid & 63;
    const int wy   = wave >> 1;     // d-direction wave coord (0..1)
    const int wx   = wave & 1;      // n-direction wave coord (0..1)
    const int l31  = lane & 31;
    const int half = lane >> 5;

    const int d0 = blockIdx.y * 128;
    const int n0 = blockIdx.x * 128;

    f32x16 acc[2][2] = {};   // [mi=d-tile][ni=n-tile]

    // staging: one global_load_lds(16B) covers 16 rows x 64 B
    const int srow   = lane >> 2;         // 0..15
    const int schunk = (lane & 3) * 8;    // shorts

    for (int kt = 0; kt < K_DIM / 64; ++kt) {
        const int kb = kt * 64;
#pragma unroll
        for (int p = 0; p < 2; ++p) {
#pragma unroll
            for (int jj = 0; jj < 2; ++jj) {
                const int j = wave * 2 + jj;   // 0..7 -> 16 rows each
                const unsigned short* ga =
                    ET + (size_t)(d0 + j * 16 + srow) * K_DIM + kb + p * 32 + schunk;
                __builtin_amdgcn_global_load_lds(
                    (const __attribute__((address_space(1))) void*)ga,
                    (__attribute__((address_space(3))) void*)(Ash + p * 4096 + j * 512),
                    16, 0, 0);
                const unsigned short* gb =
                    FB + (size_t)(n0 + j * 16 + srow) * K_DIM + kb + p * 32 + schunk;
                __builtin_amdgcn_global_load_lds(
                    (const __attribute__((address_space(1))) void*)gb,
                    (__attribute__((address_space(3))) void*)(Bsh + p * 4096 + j * 512),
                    16, 0, 0);
            }
        }
        __syncthreads();

#pragma unroll
        for (int ks = 0; ks < 4; ++ks) {
            const int p   = ks >> 1;
            const int off = (ks & 1) * 16 + half * 8;
            bf16x8 af[2], bf[2];
#pragma unroll
            for (int mi = 0; mi < 2; ++mi)
                af[mi] = *reinterpret_cast<const bf16x8*>(
                    Ash + p * 4096 + (wy * 64 + mi * 32 + l31) * 32 + off);
#pragma unroll
            for (int ni = 0; ni < 2; ++ni)
                bf[ni] = *reinterpret_cast<const bf16x8*>(
                    Bsh + p * 4096 + (wx * 64 + ni * 32 + l31) * 32 + off);
#pragma unroll
            for (int mi = 0; mi < 2; ++mi)
#pragma unroll
                for (int ni = 0; ni < 2; ++ni)
                    acc[mi][ni] = __builtin_amdgcn_mfma_f32_32x32x16_bf16(
                        af[mi], bf[ni], acc[mi][ni], 0, 0, 0);
        }
        __syncthreads();
    }

    // --- epilogue: C layout 32x32: col(n)=lane&31, row(d)=(reg&3)+8*(reg>>2)+4*half
    const int nb = n0 + wx * 64;
    float part0 = 0.f, part1 = 0.f;
#pragma unroll
    for (int mi = 0; mi < 2; ++mi) {
        const int dbase = d0 + wy * 64 + mi * 32 + 4 * half;
#pragma unroll
        for (int reg = 0; reg < 16; ++reg) {
            const int dd = dbase + (reg & 3) + 8 * (reg >> 2);
            const float bd = B[dd];
            const float* wr = W + (size_t)dd * N_DIM + nb;
            part0 += (acc[mi][0][reg] + bd) * wr[l31];
            part1 += (acc[mi][1][reg] + bd) * wr[32 + l31];
        }
    }
    part0 += __shfl_xor(part0, 32);
    part1 += __shfl_xor(part1, 32);
    if (lane < 32) {
        atomicAdd(out + nb + l31, part0);
        atomicAdd(out + nb + 32 + l31, part1);
    }
}

extern "C" void kernel_launch(void* const* d_in, const int* in_sizes, int n_in,
                              void* d_out, int out_size, void* d_ws, size_t ws_size,
                              hipStream_t stream) {
    const float* F = (const float*)d_in[0];   // features (N, K)
    const float* W = (const float*)d_in[1];   // w        (D, N)
    const float* E = (const float*)d_in[2];   // E        (K, D)
    const float* B = (const float*)d_in[3];   // b        (D,)
    float* out = (float*)d_out;               // (N,) f32

    unsigned short* ET = (unsigned short*)d_ws;                       // 4 MB
    unsigned short* FB = (unsigned short*)((char*)d_ws + (size_t)D_DIM * K_DIM * 2);  // 8 MB

    hipMemsetAsync(d_out, 0, (size_t)out_size * sizeof(float), stream);
    transpose_E<<<dim3(D_DIM / 64, K_DIM / 64), 256, 0, stream>>>(E, ET);
    convert_F<<<dim3(N_DIM * K_DIM / (256 * 8)), 256, 0, stream>>>(F, FB);
    gemm_fused<<<dim3(N_DIM / 128, D_DIM / 128), 256, 0, stream>>>(FB, W, ET, B, out);
}

// Round 3
// 241.486 us; speedup vs baseline: 1.2480x; 1.0278x over previous
//
#include <hip/hip_runtime.h>

#define N_DIM 8192   // rows of features / columns of w / output length
#define K_DIM 512    // inner dim of features @ E
#define D_DIM 4096   // columns of E / rows of w

typedef __bf16 bf16x8 __attribute__((ext_vector_type(8)));
typedef float  f32x16 __attribute__((ext_vector_type(16)));
typedef unsigned short u16x8 __attribute__((ext_vector_type(8)));

__device__ __forceinline__ unsigned short f2bf(float f) {
    union { float f; unsigned int u; } v; v.f = f;
    unsigned int r = v.u + 0x7FFF + ((v.u >> 16) & 1);   // RNE
    return (unsigned short)(r >> 16);
}

// ---------------------------------------------------------------------------
// Kernel 1: E [512][4096] f32  ->  ET [4096][512] bf16 (k-contiguous rows)
// ---------------------------------------------------------------------------
__global__ __launch_bounds__(256) void transpose_E(const float* __restrict__ E,
                                                   unsigned short* __restrict__ ET) {
    __shared__ float tile[64][65];
    const int d0 = blockIdx.x * 64;
    const int k0 = blockIdx.y * 64;
    const int tid = threadIdx.x;
    const int r  = tid / 16;          // 0..15
    const int c4 = (tid % 16) * 4;    // 0..60
#pragma unroll
    for (int p = 0; p < 4; ++p) {
        int k = p * 16 + r;
        float4 v = *reinterpret_cast<const float4*>(E + (size_t)(k0 + k) * D_DIM + d0 + c4);
        tile[k][c4 + 0] = v.x; tile[k][c4 + 1] = v.y;
        tile[k][c4 + 2] = v.z; tile[k][c4 + 3] = v.w;
    }
    __syncthreads();
#pragma unroll
    for (int p = 0; p < 4; ++p) {
        int d = p * 16 + r;
        ushort4 o;
        o.x = f2bf(tile[c4 + 0][d]);
        o.y = f2bf(tile[c4 + 1][d]);
        o.z = f2bf(tile[c4 + 2][d]);
        o.w = f2bf(tile[c4 + 3][d]);
        *reinterpret_cast<ushort4*>(ET + (size_t)(d0 + d) * K_DIM + k0 + c4) = o;
    }
}

// ---------------------------------------------------------------------------
// Kernel 2: F [8192][512] f32 -> FB bf16, same layout (k-contiguous rows)
// ---------------------------------------------------------------------------
__global__ __launch_bounds__(256) void convert_F(const float* __restrict__ F,
                                                 unsigned short* __restrict__ FB) {
    const int idx8 = (blockIdx.x * 256 + threadIdx.x) * 8;
    float4 a = *reinterpret_cast<const float4*>(F + idx8);
    float4 b = *reinterpret_cast<const float4*>(F + idx8 + 4);
    u16x8 o;
    o[0] = f2bf(a.x); o[1] = f2bf(a.y); o[2] = f2bf(a.z); o[3] = f2bf(a.w);
    o[4] = f2bf(b.x); o[5] = f2bf(b.y); o[6] = f2bf(b.z); o[7] = f2bf(b.w);
    *reinterpret_cast<u16x8*>(FB + idx8) = o;
}

// ---------------------------------------------------------------------------
// Kernel 3: fused  out[n] = sum_d (F@E + b)[n,d] * w[d,n], computed as y^T:
// C-tile 128(d-rows) x 128(n-cols), BK=64 (two 32-k panels of 64B rows),
// 4 waves (2x2), 32x32x16 bf16 MFMA. C cols = n -> coalesced W epilogue.
//
// LDS bank-conflict fix: chunk c (16B) of local row r lives at slot
// c ^ ((r>>1)&3). Implemented source-side for global_load_lds (each staging
// lane fetches the swizzled global chunk); readers recompute the slot.
// Bank base = 16(r&1) + 4(c^((r>>1)&3)) -> uniform over 8 bank-groups,
// b128 wave64 read = 8 phases (theoretical min).
// ---------------------------------------------------------------------------
__global__ __launch_bounds__(256) void gemm_fused(const unsigned short* __restrict__ FB,
                                                  const float* __restrict__ W,
                                                  const unsigned short* __restrict__ ET,
                                                  const float* __restrict__ B,
                                                  float* __restrict__ out) {
    __shared__ unsigned short Ash[2 * 128 * 32];  // ET tile: rows = d
    __shared__ unsigned short Bsh[2 * 128 * 32];  // FB tile: rows = n

    const int tid  = threadIdx.x;
    const int wave = tid >> 6;
    const int lane = tid & 63;
    const int wy   = wave >> 1;     // d-direction wave coord (0..1)
    const int wx   = wave & 1;      // n-direction wave coord (0..1)
    const int l31  = lane & 31;
    const int half = lane >> 5;

    const int d0 = blockIdx.y * 128;
    const int n0 = blockIdx.x * 128;

    f32x16 acc[2][2] = {};   // [mi=d-tile][ni=n-tile]

    // staging: one global_load_lds(16B) covers 16 rows x 64 B
    const int srow   = lane >> 2;                          // 0..15 (local row % 16)
    const int schunk = (((lane & 3) ^ ((srow >> 1) & 3)) * 8);  // swizzled global chunk (shorts)

    for (int kt = 0; kt < K_DIM / 64; ++kt) {
        const int kb = kt * 64;
#pragma unroll
        for (int p = 0; p < 2; ++p) {
#pragma unroll
            for (int jj = 0; jj < 2; ++jj) {
                const int j = wave * 2 + jj;   // 0..7 -> 16 rows each
                // j*16 is a multiple of 8 -> ((j*16+srow)>>1)&3 == (srow>>1)&3
                const unsigned short* ga =
                    ET + (size_t)(d0 + j * 16 + srow) * K_DIM + kb + p * 32 + schunk;
                __builtin_amdgcn_global_load_lds(
                    (const __attribute__((address_space(1))) void*)ga,
                    (__attribute__((address_space(3))) void*)(Ash + p * 4096 + j * 512),
                    16, 0, 0);
                const unsigned short* gb =
                    FB + (size_t)(n0 + j * 16 + srow) * K_DIM + kb + p * 32 + schunk;
                __builtin_amdgcn_global_load_lds(
                    (const __attribute__((address_space(1))) void*)gb,
                    (__attribute__((address_space(3))) void*)(Bsh + p * 4096 + j * 512),
                    16, 0, 0);
            }
        }
        __syncthreads();

#pragma unroll
        for (int ks = 0; ks < 4; ++ks) {
            const int p = ks >> 1;
            const int c = (ks & 1) * 2 + half;   // 16B chunk index within row
            bf16x8 af[2], bf[2];
#pragma unroll
            for (int mi = 0; mi < 2; ++mi) {
                const int R = wy * 64 + mi * 32 + l31;
                const int slot = c ^ ((R >> 1) & 3);
                af[mi] = *reinterpret_cast<const bf16x8*>(
                    Ash + p * 4096 + R * 32 + slot * 8);
            }
#pragma unroll
            for (int ni = 0; ni < 2; ++ni) {
                const int R = wx * 64 + ni * 32 + l31;
                const int slot = c ^ ((R >> 1) & 3);
                bf[ni] = *reinterpret_cast<const bf16x8*>(
                    Bsh + p * 4096 + R * 32 + slot * 8);
            }
#pragma unroll
            for (int mi = 0; mi < 2; ++mi)
#pragma unroll
                for (int ni = 0; ni < 2; ++ni)
                    acc[mi][ni] = __builtin_amdgcn_mfma_f32_32x32x16_bf16(
                        af[mi], bf[ni], acc[mi][ni], 0, 0, 0);
        }
        __syncthreads();
    }

    // --- epilogue: C layout 32x32: col(n)=lane&31, row(d)=(reg&3)+8*(reg>>2)+4*half
    const int nb = n0 + wx * 64;
    float part0 = 0.f, part1 = 0.f;
#pragma unroll
    for (int mi = 0; mi < 2; ++mi) {
        const int dbase = d0 + wy * 64 + mi * 32 + 4 * half;
#pragma unroll
        for (int reg = 0; reg < 16; ++reg) {
            const int dd = dbase + (reg & 3) + 8 * (reg >> 2);
            const float bd = B[dd];
            const float* wr = W + (size_t)dd * N_DIM + nb;
            part0 += (acc[mi][0][reg] + bd) * wr[l31];
            part1 += (acc[mi][1][reg] + bd) * wr[32 + l31];
        }
    }
    part0 += __shfl_xor(part0, 32);
    part1 += __shfl_xor(part1, 32);
    if (lane < 32) {
        atomicAdd(out + nb + l31, part0);
        atomicAdd(out + nb + 32 + l31, part1);
    }
}

extern "C" void kernel_launch(void* const* d_in, const int* in_sizes, int n_in,
                              void* d_out, int out_size, void* d_ws, size_t ws_size,
                              hipStream_t stream) {
    const float* F = (const float*)d_in[0];   // features (N, K)
    const float* W = (const float*)d_in[1];   // w        (D, N)
    const float* E = (const float*)d_in[2];   // E        (K, D)
    const float* B = (const float*)d_in[3];   // b        (D,)
    float* out = (float*)d_out;               // (N,) f32

    unsigned short* ET = (unsigned short*)d_ws;                       // 4 MB
    unsigned short* FB = (unsigned short*)((char*)d_ws + (size_t)D_DIM * K_DIM * 2);  // 8 MB

    hipMemsetAsync(d_out, 0, (size_t)out_size * sizeof(float), stream);
    transpose_E<<<dim3(D_DIM / 64, K_DIM / 64), 256, 0, stream>>>(E, ET);
    convert_F<<<dim3(N_DIM * K_DIM / (256 * 8)), 256, 0, stream>>>(F, FB);
    gemm_fused<<<dim3(N_DIM / 128, D_DIM / 128), 256, 0, stream>>>(FB, W, ET, B, out);
}

// Round 4
// 237.304 us; speedup vs baseline: 1.2700x; 1.0176x over previous
//
#include <hip/hip_runtime.h>

#define N_DIM 8192   // rows of features / columns of w / output length
#define K_DIM 512    // inner dim of features @ E
#define D_DIM 4096   // columns of E / rows of w

typedef __bf16 bf16x8 __attribute__((ext_vector_type(8)));
typedef float  f32x16 __attribute__((ext_vector_type(16)));
typedef unsigned short u16x8 __attribute__((ext_vector_type(8)));

__device__ __forceinline__ unsigned short f2bf(float f) {
    union { float f; unsigned int u; } v; v.f = f;
    unsigned int r = v.u + 0x7FFF + ((v.u >> 16) & 1);   // RNE
    return (unsigned short)(r >> 16);
}

// ---------------------------------------------------------------------------
// Kernel 1: E [512][4096] f32  ->  ET [4096][512] bf16 (k-contiguous rows)
// ---------------------------------------------------------------------------
__global__ __launch_bounds__(256) void transpose_E(const float* __restrict__ E,
                                                   unsigned short* __restrict__ ET) {
    __shared__ float tile[64][65];
    const int d0 = blockIdx.x * 64;
    const int k0 = blockIdx.y * 64;
    const int tid = threadIdx.x;
    const int r  = tid / 16;          // 0..15
    const int c4 = (tid % 16) * 4;    // 0..60
#pragma unroll
    for (int p = 0; p < 4; ++p) {
        int k = p * 16 + r;
        float4 v = *reinterpret_cast<const float4*>(E + (size_t)(k0 + k) * D_DIM + d0 + c4);
        tile[k][c4 + 0] = v.x; tile[k][c4 + 1] = v.y;
        tile[k][c4 + 2] = v.z; tile[k][c4 + 3] = v.w;
    }
    __syncthreads();
#pragma unroll
    for (int p = 0; p < 4; ++p) {
        int d = p * 16 + r;
        ushort4 o;
        o.x = f2bf(tile[c4 + 0][d]);
        o.y = f2bf(tile[c4 + 1][d]);
        o.z = f2bf(tile[c4 + 2][d]);
        o.w = f2bf(tile[c4 + 3][d]);
        *reinterpret_cast<ushort4*>(ET + (size_t)(d0 + d) * K_DIM + k0 + c4) = o;
    }
}

// ---------------------------------------------------------------------------
// Kernel 2: F [8192][512] f32 -> FB bf16, same layout (k-contiguous rows)
// ---------------------------------------------------------------------------
__global__ __launch_bounds__(256) void convert_F(const float* __restrict__ F,
                                                 unsigned short* __restrict__ FB) {
    const int idx8 = (blockIdx.x * 256 + threadIdx.x) * 8;
    float4 a = *reinterpret_cast<const float4*>(F + idx8);
    float4 b = *reinterpret_cast<const float4*>(F + idx8 + 4);
    u16x8 o;
    o[0] = f2bf(a.x); o[1] = f2bf(a.y); o[2] = f2bf(a.z); o[3] = f2bf(a.w);
    o[4] = f2bf(b.x); o[5] = f2bf(b.y); o[6] = f2bf(b.z); o[7] = f2bf(b.w);
    *reinterpret_cast<u16x8*>(FB + idx8) = o;
}

// ---------------------------------------------------------------------------
// Kernel 3: fused  out[n] = sum_d (F@E + b)[n,d] * w[d,n], computed as y^T:
// C-tile 128(d-rows) x 128(n-cols), BK=64, 4 waves (2x2), 32x32x16 bf16 MFMA.
//
// R4: XCD-rectangle swizzle — flat block id f: XCD = f%8 (dispatch heuristic).
// XCD x gets n-band (x&3)*16 tiles x d-band (x>>2)*16 tiles, so its staging
// working set is FB 2 MB + ET 2 MB = 4 MB = its private L2. The read-once W
// stream (134 MB) uses non-temporal loads so it can't evict the rectangle.
// ---------------------------------------------------------------------------
__global__ __launch_bounds__(256) void gemm_fused(const unsigned short* __restrict__ FB,
                                                  const float* __restrict__ W,
                                                  const unsigned short* __restrict__ ET,
                                                  const float* __restrict__ B,
                                                  float* __restrict__ out) {
    __shared__ unsigned short Ash[2 * 128 * 32];  // ET tile: rows = d
    __shared__ unsigned short Bsh[2 * 128 * 32];  // FB tile: rows = n

    const int tid  = threadIdx.x;
    const int wave = tid >> 6;
    const int lane = tid & 63;
    const int wy   = wave >> 1;     // d-direction wave coord (0..1)
    const int wx   = wave & 1;      // n-direction wave coord (0..1)
    const int l31  = lane & 31;
    const int half = lane >> 5;

    // --- XCD-rectangle swizzle (bijection on 64x32 grid) ---
    const int f   = blockIdx.x + ((int)gridDim.x) * blockIdx.y;  // dispatch order
    const int xcd = f & 7;
    const int s   = f >> 3;               // 0..255 within XCD
    const int ntile = (xcd & 3) * 16 + (s & 15);   // 0..63
    const int dtile = (xcd >> 2) * 16 + (s >> 4);  // 0..31
    const int n0 = ntile * 128;
    const int d0 = dtile * 128;

    f32x16 acc[2][2] = {};   // [mi=d-tile][ni=n-tile]

    // staging: one global_load_lds(16B) covers 16 rows x 64 B
    const int srow   = lane >> 2;                               // 0..15
    const int schunk = (((lane & 3) ^ ((srow >> 1) & 3)) * 8);  // swizzled chunk (shorts)

    for (int kt = 0; kt < K_DIM / 64; ++kt) {
        const int kb = kt * 64;
#pragma unroll
        for (int p = 0; p < 2; ++p) {
#pragma unroll
            for (int jj = 0; jj < 2; ++jj) {
                const int j = wave * 2 + jj;   // 0..7 -> 16 rows each
                const unsigned short* ga =
                    ET + (size_t)(d0 + j * 16 + srow) * K_DIM + kb + p * 32 + schunk;
                __builtin_amdgcn_global_load_lds(
                    (const __attribute__((address_space(1))) void*)ga,
                    (__attribute__((address_space(3))) void*)(Ash + p * 4096 + j * 512),
                    16, 0, 0);
                const unsigned short* gb =
                    FB + (size_t)(n0 + j * 16 + srow) * K_DIM + kb + p * 32 + schunk;
                __builtin_amdgcn_global_load_lds(
                    (const __attribute__((address_space(1))) void*)gb,
                    (__attribute__((address_space(3))) void*)(Bsh + p * 4096 + j * 512),
                    16, 0, 0);
            }
        }
        __syncthreads();

#pragma unroll
        for (int ks = 0; ks < 4; ++ks) {
            const int p = ks >> 1;
            const int c = (ks & 1) * 2 + half;   // 16B chunk index within row
            bf16x8 af[2], bf[2];
#pragma unroll
            for (int mi = 0; mi < 2; ++mi) {
                const int R = wy * 64 + mi * 32 + l31;
                const int slot = c ^ ((R >> 1) & 3);
                af[mi] = *reinterpret_cast<const bf16x8*>(
                    Ash + p * 4096 + R * 32 + slot * 8);
            }
#pragma unroll
            for (int ni = 0; ni < 2; ++ni) {
                const int R = wx * 64 + ni * 32 + l31;
                const int slot = c ^ ((R >> 1) & 3);
                bf[ni] = *reinterpret_cast<const bf16x8*>(
                    Bsh + p * 4096 + R * 32 + slot * 8);
            }
#pragma unroll
            for (int mi = 0; mi < 2; ++mi)
#pragma unroll
                for (int ni = 0; ni < 2; ++ni)
                    acc[mi][ni] = __builtin_amdgcn_mfma_f32_32x32x16_bf16(
                        af[mi], bf[ni], acc[mi][ni], 0, 0, 0);
        }
        __syncthreads();
    }

    // --- epilogue: C layout 32x32: col(n)=lane&31, row(d)=(reg&3)+8*(reg>>2)+4*half
    // W is read exactly once device-wide -> non-temporal (don't evict L2 rectangle)
    const int nb = n0 + wx * 64;
    float part0 = 0.f, part1 = 0.f;
#pragma unroll
    for (int mi = 0; mi < 2; ++mi) {
        const int dbase = d0 + wy * 64 + mi * 32 + 4 * half;
#pragma unroll
        for (int reg = 0; reg < 16; ++reg) {
            const int dd = dbase + (reg & 3) + 8 * (reg >> 2);
            const float bd = B[dd];
            const float* wr = W + (size_t)dd * N_DIM + nb;
            part0 += (acc[mi][0][reg] + bd) * __builtin_nontemporal_load(wr + l31);
            part1 += (acc[mi][1][reg] + bd) * __builtin_nontemporal_load(wr + 32 + l31);
        }
    }
    part0 += __shfl_xor(part0, 32);
    part1 += __shfl_xor(part1, 32);
    if (lane < 32) {
        atomicAdd(out + nb + l31, part0);
        atomicAdd(out + nb + 32 + l31, part1);
    }
}

extern "C" void kernel_launch(void* const* d_in, const int* in_sizes, int n_in,
                              void* d_out, int out_size, void* d_ws, size_t ws_size,
                              hipStream_t stream) {
    const float* F = (const float*)d_in[0];   // features (N, K)
    const float* W = (const float*)d_in[1];   // w        (D, N)
    const float* E = (const float*)d_in[2];   // E        (K, D)
    const float* B = (const float*)d_in[3];   // b        (D,)
    float* out = (float*)d_out;               // (N,) f32

    unsigned short* ET = (unsigned short*)d_ws;                       // 4 MB
    unsigned short* FB = (unsigned short*)((char*)d_ws + (size_t)D_DIM * K_DIM * 2);  // 8 MB

    hipMemsetAsync(d_out, 0, (size_t)out_size * sizeof(float), stream);
    transpose_E<<<dim3(D_DIM / 64, K_DIM / 64), 256, 0, stream>>>(E, ET);
    convert_F<<<dim3(N_DIM * K_DIM / (256 * 8)), 256, 0, stream>>>(F, FB);
    gemm_fused<<<dim3(N_DIM / 128, D_DIM / 128), 256, 0, stream>>>(FB, W, ET, B, out);
}